// Round 1
// baseline (88.765 us; speedup 1.0000x reference)
//
#include <hip/hip_runtime.h>
#include <math.h>

#define BB 4
#define SS 1024
#define LL 128
#define PADL (LL + 4)   // stride 132 floats: 16B-aligned rows, bank (4i+j)%32
#define NBLK 128

// Self-resetting arrival counter. Lives in module .bss (NOT in d_ws, which the
// harness poisons every iteration). Zero-initialized at module load; the last
// block to arrive resets it to 0 for the next launch, so graph replays work.
__device__ int g_arrive = 0;

// One fused kernel, 128 blocks x 512 threads.
// Phase 1 (all blocks): 32 pred rows each -> row-LSE -> emit partial
//   ws_part[block]; blocks {0,32,64,96} wave 0 stash exp(logp0) -> ws_elp.
// Arrival: device-scope atomicAdd; last block acquires and runs the finish
//   (identical math to the previous 2-kernel version, incl. recomputing the
//   transition row-log-softmax in LDS instead of reading ws_trans).
__global__ __launch_bounds__(512) void crf_fused_kernel(
    const float* __restrict__ pred,
    const int* __restrict__ gt,
    const float* __restrict__ transition,
    float* __restrict__ ws_part,   // 128 floats
    float* __restrict__ ws_elp,    // 512 floats
    float* __restrict__ out)
{
    __shared__ float tr_s[LL][PADL];   // raw transition, then log-softmaxed in place
    __shared__ float lse_s[LL];        // per-row LSE of transition
    __shared__ float elp_s[BB][LL];
    __shared__ float pc[4][LL];        // column exp-sum partials (c)
    __shared__ float pa[4][BB][LL];    // column exp-sum partials (alpha)
    __shared__ float emit_s[BB];
    __shared__ float wred[8];          // gold per-wave partials
    __shared__ float fm[8], fs[8];     // forward LSE per-wave partials
    __shared__ float red[8];           // phase-1 per-wave emit partials
    __shared__ int   last_s;

    const int tid  = threadIdx.x;
    const int wave = tid >> 6;
    const int lane = tid & 63;
    const int row0 = blockIdx.x * 32;

    // ---------------- phase 1: 32 pred rows per block ----------------
    // issue all global loads up front so latencies overlap
    int gi[4];
    #pragma unroll
    for (int it = 0; it < 4; ++it) gi[it] = gt[row0 + it * 8 + wave];
    float2 v[4];
    #pragma unroll
    for (int it = 0; it < 4; ++it)
        v[it] = ((const float2*)(pred + (size_t)(row0 + it * 8 + wave) * LL))[lane];

    float local = 0.f;
    #pragma unroll
    for (int it = 0; it < 4; ++it) {
        float m = fmaxf(v[it].x, v[it].y);
        #pragma unroll
        for (int off = 32; off > 0; off >>= 1) m = fmaxf(m, __shfl_xor(m, off));
        float s = __expf(v[it].x - m) + __expf(v[it].y - m);
        #pragma unroll
        for (int off = 32; off > 0; off >>= 1) s += __shfl_xor(s, off);
        const float lse = m + __logf(s);

        // pred[r][g] is already in-wave: lane g>>1 holds it (component g&1)
        const int g = gi[it];                    // uniform across wave
        const float hold = (g & 1) ? v[it].y : v[it].x;
        local += __shfl(hold, g >> 1) - lse;

        // t == 0 rows live in blocks {0,32,64,96}: stash exp(logp0)
        if (it == 0 && wave == 0 && (blockIdx.x & 31) == 0) {
            const int b = blockIdx.x >> 5;
            float2 o;
            o.x = __expf(v[0].x - lse);
            o.y = __expf(v[0].y - lse);
            ((float2*)(ws_elp + b * LL))[lane] = o;
        }
    }
    if (lane == 0) red[wave] = local;
    __threadfence();                    // release ws_elp writes to device scope
    __syncthreads();
    if (tid == 0) {
        ws_part[blockIdx.x] = red[0] + red[1] + red[2] + red[3]
                            + red[4] + red[5] + red[6] + red[7];
        __threadfence();                // release ws_part
        const int old = atomicAdd(&g_arrive, 1);
        last_s = (old == NBLK - 1);
        if (last_s) atomicExch(&g_arrive, 0);   // reset for next launch
    }
    __syncthreads();
    if (!last_s) return;
    __threadfence();                    // acquire: see other blocks' ws writes

    // ---------------- finish (last block only, 512 threads) ----------------
    // ---- issue gold-path gt loads FIRST (latency hides behind staging) ----
    const int gb = tid >> 7;           // batch 0..3
    const int t0 = tid & (LL - 1);
    int gf[8], gs[8];
    {
        const int* gtb = gt + gb * SS;
        #pragma unroll
        for (int k = 0; k < 8; ++k) {
            const int t = t0 + k * LL;
            const bool val = (t < SS - 1);
            gf[k] = val ? gtb[t]     : 0;
            gs[k] = val ? gtb[t + 1] : 0;
        }
    }

    // ---- stage RAW transition / elp / emit ----
    #pragma unroll
    for (int k = 0; k < 8; ++k) {               // 4096 float4s, 8 per thread
        const int e = (tid + k * 512) * 4;      // element index
        const int i = e >> 7, j = e & (LL - 1);
        *(float4*)&tr_s[i][j] = ((const float4*)transition)[e >> 2];
    }
    elp_s[tid >> 7][tid & (LL - 1)] = ws_elp[tid];
    if (wave < BB) {                            // emit: wave w reduces batch w
        float p = (lane < 32) ? ws_part[wave * 32 + lane] : 0.f;
        #pragma unroll
        for (int off = 32; off > 0; off >>= 1) p += __shfl_xor(p, off);
        if (lane == 0) emit_s[wave] = p;
    }
    __syncthreads();                                        // (A0)

    // ---- transition row log-softmax, in place: wave w owns rows w*16..w*16+15
    #pragma unroll
    for (int k = 0; k < 16; ++k) {
        const int r = wave * 16 + k;
        const float a = tr_s[r][lane];
        const float b = tr_s[r][lane + 64];
        float m = fmaxf(a, b);
        #pragma unroll
        for (int off = 32; off > 0; off >>= 1) m = fmaxf(m, __shfl_xor(m, off));
        float s = __expf(a - m) + __expf(b - m);
        #pragma unroll
        for (int off = 32; off > 0; off >>= 1) s += __shfl_xor(s, off);
        if (lane == 0) lse_s[r] = m + __logf(s);
    }
    __syncthreads();                                        // (A1)
    #pragma unroll
    for (int k = 0; k < 8; ++k) {               // subtract row LSE in place
        const int e = (tid + k * 512) * 4;
        const int i = e >> 7, j = e & (LL - 1);
        float4 t4 = *(float4*)&tr_s[i][j];
        const float l = lse_s[i];
        t4.x -= l; t4.y -= l; t4.z -= l; t4.w -= l;
        *(float4*)&tr_s[i][j] = t4;
    }
    __syncthreads();                                        // (A)

    // ---- column partials: thread (sub,j), sub owns 32 rows ----
    {
        const int sub = tid >> 7;
        const int j   = tid & (LL - 1);
        float sc = 0.f, s0 = 0.f, s1 = 0.f, s2 = 0.f, s3 = 0.f;
        #pragma unroll
        for (int k = 0; k < 32; ++k) {
            const int i = sub * 32 + k;
            const float e = __expf(tr_s[i][j]);
            sc += e;
            s0 += e * elp_s[0][i];
            s1 += e * elp_s[1][i];
            s2 += e * elp_s[2][i];
            s3 += e * elp_s[3][i];
        }
        pc[sub][j] = sc;
        pa[sub][0][j] = s0; pa[sub][1][j] = s1;
        pa[sub][2][j] = s2; pa[sub][3][j] = s3;
    }
    // ---- gold path partials from prefetched indices (tr_s read-only) ----
    {
        float g = 0.f;
        #pragma unroll
        for (int k = 0; k < 8; ++k) {
            const int t = t0 + k * LL;
            if (t < SS - 1) g += tr_s[gf[k]][gs[k]];
        }
        #pragma unroll
        for (int off = 32; off > 0; off >>= 1) g += __shfl_xor(g, off);
        if (lane == 0) wred[wave] = g;
    }
    __syncthreads();                                        // (B)

    // ---- alpha[b,j] + per-wave forward LSE partials ----
    {
        const int b = tid >> 7;
        const int j = tid & (LL - 1);
        const float csum = pc[0][j] + pc[1][j] + pc[2][j] + pc[3][j];
        const float asum = pa[0][b][j] + pa[1][b][j] + pa[2][b][j] + pa[3][b][j];
        const float alpha = __logf(asum) + (float)(SS - 2) * __logf(csum);

        float wm = alpha;
        #pragma unroll
        for (int off = 32; off > 0; off >>= 1) wm = fmaxf(wm, __shfl_xor(wm, off));
        float wsum = __expf(alpha - wm);
        #pragma unroll
        for (int off = 32; off > 0; off >>= 1) wsum += __shfl_xor(wsum, off);
        if (lane == 0) { fm[wave] = wm; fs[wave] = wsum; }
    }
    __syncthreads();                                        // (C)

    if (tid < BB) {
        const float m0 = fm[2 * tid], m1 = fm[2 * tid + 1];
        const float mm = fmaxf(m0, m1);
        const float fwd = mm + __logf(fs[2 * tid] * __expf(m0 - mm)
                                    + fs[2 * tid + 1] * __expf(m1 - mm));
        const float gold = wred[2 * tid] + wred[2 * tid + 1];
        fm[tid] = emit_s[tid] + gold - fwd;   // reuse fm as loss scratch
    }
    __syncthreads();                                        // (D)
    if (tid == 0)
        out[0] = -(fm[0] + fm[1] + fm[2] + fm[3]) * (1.0f / BB);
}

extern "C" void kernel_launch(void* const* d_in, const int* in_sizes, int n_in,
                              void* d_out, int out_size, void* d_ws, size_t ws_size,
                              hipStream_t stream) {
    const float* pred       = (const float*)d_in[0];
    const int*   gt         = (const int*)d_in[1];
    const float* transition = (const float*)d_in[2];
    float* out = (float*)d_out;

    float* ws_part = (float*)d_ws;     // 128 floats
    float* ws_elp  = ws_part + 128;    // 512 floats, 512B offset (16B aligned)

    crf_fused_kernel<<<NBLK, 512, 0, stream>>>(
        pred, gt, transition, ws_part, ws_elp, out);
}

// Round 2
// 73.798 us; speedup vs baseline: 1.2028x; 1.2028x over previous
//
#include <hip/hip_runtime.h>
#include <math.h>

#define BB 4
#define SS 1024
#define LL 128
#define PADL (LL + 4)   // stride 132 floats: 16B-aligned rows, bank (4i+j)%32
#define NBLK 128

// Cross-block state lives in module .bss (NOT in d_ws, which the harness
// poisons every iteration). All accesses are device(agent)-scope atomics, so
// no __threadfence (= no buffer_wbl2 L2 writeback) is ever needed.
__device__ int   g_arrive = 0;
__device__ float g_part[NBLK];

// One fused kernel, 128 blocks x 512 threads.
// Phase 1 (all blocks): 32 pred rows each -> row-LSE -> emit partial ->
//   atomicExch into g_part[block]; arrival via atomicAdd.
// Last block to arrive runs the finish: recomputes exp(logp0) rows from pred,
//   row-log-softmaxes transition in LDS, column partials, alpha, loss.
__global__ __launch_bounds__(512) void crf_fused_kernel(
    const float* __restrict__ pred,
    const int* __restrict__ gt,
    const float* __restrict__ transition,
    float* __restrict__ out)
{
    __shared__ float tr_s[LL][PADL];   // raw transition, then log-softmaxed in place
    __shared__ float lse_s[LL];        // per-row LSE of transition
    __shared__ float elp_s[BB][LL];
    __shared__ float pc[4][LL];        // column exp-sum partials (c)
    __shared__ float pa[4][BB][LL];    // column exp-sum partials (alpha)
    __shared__ float emit_s[BB];
    __shared__ float wred[8];          // gold per-wave partials
    __shared__ float fm[8], fs[8];     // forward LSE per-wave partials
    __shared__ float red[8];           // phase-1 per-wave emit partials
    __shared__ int   last_s;

    const int tid  = threadIdx.x;
    const int wave = tid >> 6;
    const int lane = tid & 63;
    const int row0 = blockIdx.x * 32;

    // ---------------- phase 1: 32 pred rows per block ----------------
    int gi[4];
    #pragma unroll
    for (int it = 0; it < 4; ++it) gi[it] = gt[row0 + it * 8 + wave];
    float2 v[4];
    #pragma unroll
    for (int it = 0; it < 4; ++it)
        v[it] = ((const float2*)(pred + (size_t)(row0 + it * 8 + wave) * LL))[lane];

    float local = 0.f;
    #pragma unroll
    for (int it = 0; it < 4; ++it) {
        float m = fmaxf(v[it].x, v[it].y);
        #pragma unroll
        for (int off = 32; off > 0; off >>= 1) m = fmaxf(m, __shfl_xor(m, off));
        float s = __expf(v[it].x - m) + __expf(v[it].y - m);
        #pragma unroll
        for (int off = 32; off > 0; off >>= 1) s += __shfl_xor(s, off);
        const float lse = m + __logf(s);

        // pred[r][g] is already in-wave: lane g>>1 holds it (component g&1)
        const int g = gi[it];                    // uniform across wave
        const float hold = (g & 1) ? v[it].y : v[it].x;
        local += __shfl(hold, g >> 1) - lse;
    }
    if (lane == 0) red[wave] = local;
    __syncthreads();
    if (tid == 0) {
        const float part = red[0] + red[1] + red[2] + red[3]
                         + red[4] + red[5] + red[6] + red[7];
        // release: agent-scope atomic swap goes to the coherence point; consume
        // its return value so vmcnt(0) proves completion BEFORE the arrival add.
        const float old = atomicExch(&g_part[blockIdx.x], part);
        asm volatile("s_waitcnt vmcnt(0)" :: "v"(old) : "memory");
        const int prev = atomicAdd(&g_arrive, 1);
        last_s = (prev == NBLK - 1);
        if (last_s) atomicExch(&g_arrive, 0);   // reset for next launch
    }
    __syncthreads();
    if (!last_s) return;
    asm volatile("" ::: "memory");     // no hoisting of reads above the gate

    // ---------------- finish (last block only, 512 threads) ----------------
    // ---- issue gold-path gt loads FIRST (latency hides behind staging) ----
    const int gb = tid >> 7;           // batch 0..3
    const int t0 = tid & (LL - 1);
    int gf[8], gs[8];
    {
        const int* gtb = gt + gb * SS;
        #pragma unroll
        for (int k = 0; k < 8; ++k) {
            const int t = t0 + k * LL;
            const bool val = (t < SS - 1);
            gf[k] = val ? gtb[t]     : 0;
            gs[k] = val ? gtb[t + 1] : 0;
        }
    }

    // ---- stage RAW transition ----
    #pragma unroll
    for (int k = 0; k < 8; ++k) {               // 4096 float4s, 8 per thread
        const int e = (tid + k * 512) * 4;      // element index
        const int i = e >> 7, j = e & (LL - 1);
        *(float4*)&tr_s[i][j] = ((const float4*)transition)[e >> 2];
    }

    if (wave < 4) {
        // ---- emit: wave w reduces batch w's 32 partials (agent atomic loads)
        float p = 0.f;
        if (lane < 32)
            p = __hip_atomic_load(&g_part[wave * 32 + lane],
                                  __ATOMIC_RELAXED, __HIP_MEMORY_SCOPE_AGENT);
        #pragma unroll
        for (int off = 32; off > 0; off >>= 1) p += __shfl_xor(p, off);
        if (lane == 0) emit_s[wave] = p;
    } else {
        // ---- elp: wave 4+b recomputes exp(logp0) for batch b from pred ----
        const int b = wave - 4;
        const float2 vv = ((const float2*)(pred + (size_t)b * SS * LL))[lane];
        float m = fmaxf(vv.x, vv.y);
        #pragma unroll
        for (int off = 32; off > 0; off >>= 1) m = fmaxf(m, __shfl_xor(m, off));
        float s = __expf(vv.x - m) + __expf(vv.y - m);
        #pragma unroll
        for (int off = 32; off > 0; off >>= 1) s += __shfl_xor(s, off);
        const float lse = m + __logf(s);
        elp_s[b][2 * lane]     = __expf(vv.x - lse);
        elp_s[b][2 * lane + 1] = __expf(vv.y - lse);
    }
    __syncthreads();                                        // (A0)

    // ---- transition row log-softmax, in place: wave w owns rows w*16..w*16+15
    #pragma unroll
    for (int k = 0; k < 16; ++k) {
        const int r = wave * 16 + k;
        const float a = tr_s[r][lane];
        const float b = tr_s[r][lane + 64];
        float m = fmaxf(a, b);
        #pragma unroll
        for (int off = 32; off > 0; off >>= 1) m = fmaxf(m, __shfl_xor(m, off));
        float s = __expf(a - m) + __expf(b - m);
        #pragma unroll
        for (int off = 32; off > 0; off >>= 1) s += __shfl_xor(s, off);
        if (lane == 0) lse_s[r] = m + __logf(s);
    }
    __syncthreads();                                        // (A1)
    #pragma unroll
    for (int k = 0; k < 8; ++k) {               // subtract row LSE in place
        const int e = (tid + k * 512) * 4;
        const int i = e >> 7, j = e & (LL - 1);
        float4 t4 = *(float4*)&tr_s[i][j];
        const float l = lse_s[i];
        t4.x -= l; t4.y -= l; t4.z -= l; t4.w -= l;
        *(float4*)&tr_s[i][j] = t4;
    }
    __syncthreads();                                        // (A)

    // ---- column partials: thread (sub,j), sub owns 32 rows ----
    {
        const int sub = tid >> 7;
        const int j   = tid & (LL - 1);
        float sc = 0.f, s0 = 0.f, s1 = 0.f, s2 = 0.f, s3 = 0.f;
        #pragma unroll
        for (int k = 0; k < 32; ++k) {
            const int i = sub * 32 + k;
            const float e = __expf(tr_s[i][j]);
            sc += e;
            s0 += e * elp_s[0][i];
            s1 += e * elp_s[1][i];
            s2 += e * elp_s[2][i];
            s3 += e * elp_s[3][i];
        }
        pc[sub][j] = sc;
        pa[sub][0][j] = s0; pa[sub][1][j] = s1;
        pa[sub][2][j] = s2; pa[sub][3][j] = s3;
    }
    // ---- gold path partials from prefetched indices (tr_s read-only) ----
    {
        float g = 0.f;
        #pragma unroll
        for (int k = 0; k < 8; ++k) {
            const int t = t0 + k * LL;
            if (t < SS - 1) g += tr_s[gf[k]][gs[k]];
        }
        #pragma unroll
        for (int off = 32; off > 0; off >>= 1) g += __shfl_xor(g, off);
        if (lane == 0) wred[wave] = g;
    }
    __syncthreads();                                        // (B)

    // ---- alpha[b,j] + per-wave forward LSE partials ----
    {
        const int b = tid >> 7;
        const int j = tid & (LL - 1);
        const float csum = pc[0][j] + pc[1][j] + pc[2][j] + pc[3][j];
        const float asum = pa[0][b][j] + pa[1][b][j] + pa[2][b][j] + pa[3][b][j];
        const float alpha = __logf(asum) + (float)(SS - 2) * __logf(csum);

        float wm = alpha;
        #pragma unroll
        for (int off = 32; off > 0; off >>= 1) wm = fmaxf(wm, __shfl_xor(wm, off));
        float wsum = __expf(alpha - wm);
        #pragma unroll
        for (int off = 32; off > 0; off >>= 1) wsum += __shfl_xor(wsum, off);
        if (lane == 0) { fm[wave] = wm; fs[wave] = wsum; }
    }
    __syncthreads();                                        // (C)

    if (tid < BB) {
        const float m0 = fm[2 * tid], m1 = fm[2 * tid + 1];
        const float mm = fmaxf(m0, m1);
        const float fwd = mm + __logf(fs[2 * tid] * __expf(m0 - mm)
                                    + fs[2 * tid + 1] * __expf(m1 - mm));
        const float gold = wred[2 * tid] + wred[2 * tid + 1];
        fm[tid] = emit_s[tid] + gold - fwd;   // reuse fm as loss scratch
    }
    __syncthreads();                                        // (D)
    if (tid == 0)
        out[0] = -(fm[0] + fm[1] + fm[2] + fm[3]) * (1.0f / BB);
}

extern "C" void kernel_launch(void* const* d_in, const int* in_sizes, int n_in,
                              void* d_out, int out_size, void* d_ws, size_t ws_size,
                              hipStream_t stream) {
    const float* pred       = (const float*)d_in[0];
    const int*   gt         = (const int*)d_in[1];
    const float* transition = (const float*)d_in[2];
    float* out = (float*)d_out;
    (void)d_ws; (void)ws_size;

    crf_fused_kernel<<<NBLK, 512, 0, stream>>>(pred, gt, transition, out);
}

// Round 5
// 63.728 us; speedup vs baseline: 1.3929x; 1.1580x over previous
//
#include <hip/hip_runtime.h>
#include <math.h>

#define BB 4
#define SS 1024
#define LL 128

typedef float vf2 __attribute__((ext_vector_type(2)));
typedef float vf4 __attribute__((ext_vector_type(4)));

// ws layout (floats): [0..511] ws_part (512 block partials),
// [512..1023] ws_elp (4 x 128, exp(logp0)), [1024..17407] ws_trans
// (row-log-softmaxed transition). 1024*4 B = 4 KiB-aligned.

// Kernel 1: 512 blocks x 256 threads.
//  - every block: 8 pred rows -> row-LSE -> emit partial ws_part[block]
//  - blocks b*128 (b<4): wave 0 also writes ws_elp[b][:] = exp(pred[b,0,:]-lse)
//  - blocks r<128: wave 0 also row-log-softmaxes transition row r -> ws_trans
__global__ __launch_bounds__(256) void crf_rows_kernel(
    const float* __restrict__ pred,
    const int* __restrict__ gt,
    const float* __restrict__ transition,
    float* __restrict__ ws_part,
    float* __restrict__ ws_elp,
    float* __restrict__ ws_trans)
{
    const int wave = threadIdx.x >> 6;
    const int lane = threadIdx.x & 63;
    const int row0 = blockIdx.x * 8;

    // issue all global loads up front so latencies overlap
    int gi[2];
    #pragma unroll
    for (int it = 0; it < 2; ++it) gi[it] = gt[row0 + it * 4 + wave];
    vf2 v[2];
    #pragma unroll
    for (int it = 0; it < 2; ++it)
        v[it] = __builtin_nontemporal_load(
            ((const vf2*)(pred + (size_t)(row0 + it * 4 + wave) * LL)) + lane);
    const bool do_trans = (blockIdx.x < LL) && (wave == 0);
    vf2 tv;
    if (do_trans) tv = ((const vf2*)(transition + blockIdx.x * LL))[lane];

    float local = 0.f;
    #pragma unroll
    for (int it = 0; it < 2; ++it) {
        float m = fmaxf(v[it].x, v[it].y);
        #pragma unroll
        for (int off = 32; off > 0; off >>= 1) m = fmaxf(m, __shfl_xor(m, off));
        float s = __expf(v[it].x - m) + __expf(v[it].y - m);
        #pragma unroll
        for (int off = 32; off > 0; off >>= 1) s += __shfl_xor(s, off);
        const float lse = m + __logf(s);

        // pred[r][g] is already in-wave: lane g>>1 holds it (component g&1)
        const int g = gi[it];                    // uniform across wave
        const float hold = (g & 1) ? v[it].y : v[it].x;
        local += __shfl(hold, g >> 1) - lse;

        // t == 0 rows live in blocks {0,128,256,384}: stash exp(logp0)
        if (it == 0 && wave == 0 && (blockIdx.x & 127) == 0) {
            const int b = blockIdx.x >> 7;
            vf2 o;
            o.x = __expf(v[0].x - lse);
            o.y = __expf(v[0].y - lse);
            ((vf2*)(ws_elp + b * LL))[lane] = o;
        }
    }

    // transition row-log-softmax: block r (<128), wave 0
    if (do_trans) {
        float m = fmaxf(tv.x, tv.y);
        #pragma unroll
        for (int off = 32; off > 0; off >>= 1) m = fmaxf(m, __shfl_xor(m, off));
        float s = __expf(tv.x - m) + __expf(tv.y - m);
        #pragma unroll
        for (int off = 32; off > 0; off >>= 1) s += __shfl_xor(s, off);
        const float lse = m + __logf(s);
        vf2 o; o.x = tv.x - lse; o.y = tv.y - lse;
        ((vf2*)(ws_trans + blockIdx.x * LL))[lane] = o;
    }

    __shared__ float red[4];
    if (lane == 0) red[wave] = local;
    __syncthreads();
    if (threadIdx.x == 0)
        ws_part[blockIdx.x] = red[0] + red[1] + red[2] + red[3];
}

// Kernel 2: 1 block x 512 threads. Inputs pre-softmaxed; plain exp-sums
// (no max shift needed: tr_ls <= 0, elp <= 1), gold gathers, two short LSEs.
#define PADL (LL + 4)   // stride 132 floats: 16B-aligned rows, bank (4i+j)%32
__global__ __launch_bounds__(512) void crf_finish_kernel(
    const int* __restrict__ gt,
    const float* __restrict__ ws_part,
    const float* __restrict__ ws_elp,
    const float* __restrict__ ws_trans,
    float* __restrict__ out)
{
    __shared__ float tr_s[LL][PADL];
    __shared__ float elp_s[BB][LL];
    __shared__ float pc[4][LL];        // column exp-sum partials (c)
    __shared__ float pa[4][BB][LL];    // column exp-sum partials (alpha)
    __shared__ float emit_s[BB];
    __shared__ float wred[8];          // gold per-wave partials
    __shared__ float fm[8], fs[8];     // forward LSE per-wave partials

    const int tid  = threadIdx.x;
    const int lane = tid & 63;
    const int wave = tid >> 6;

    // ---- issue ALL scattered global loads FIRST (latency hides under staging)
    const int gb = tid >> 7;           // batch 0..3
    const int t0 = tid & (LL - 1);
    int gf[8], gs[8];
    {
        const int* gtb = gt + gb * SS;
        #pragma unroll
        for (int k = 0; k < 8; ++k) {
            const int t = t0 + k * LL;
            const bool val = (t < SS - 1);
            gf[k] = val ? gtb[t]     : 0;
            gs[k] = val ? gtb[t + 1] : 0;
        }
    }
    const float elpv = ws_elp[tid];                    // 512 = BB*LL
    vf2 pp; pp.x = 0.f; pp.y = 0.f;
    if (wave < BB) pp = ((const vf2*)ws_part)[wave * 64 + lane];  // 128/batch

    // ---- stage tr (read-once: nontemporal) ----
    #pragma unroll
    for (int k = 0; k < 8; ++k) {               // 4096 float4s, 8 per thread
        const int e = (tid + k * 512) * 4;      // element index
        const int i = e >> 7, j = e & (LL - 1);
        const vf4 t4 =
            __builtin_nontemporal_load(((const vf4*)ws_trans) + (e >> 2));
        *(vf4*)&tr_s[i][j] = t4;
    }
    elp_s[tid >> 7][tid & (LL - 1)] = elpv;
    if (wave < BB) {                            // emit: wave w reduces batch w
        float p = pp.x + pp.y;
        #pragma unroll
        for (int off = 32; off > 0; off >>= 1) p += __shfl_xor(p, off);
        if (lane == 0) emit_s[wave] = p;
    }
    __syncthreads();                                        // (A)

    // ---- column partials: thread (sub,j), sub owns 32 rows ----
    {
        const int sub = tid >> 7;
        const int j   = tid & (LL - 1);
        float sc = 0.f, s0 = 0.f, s1 = 0.f, s2 = 0.f, s3 = 0.f;
        #pragma unroll
        for (int k = 0; k < 32; ++k) {
            const int i = sub * 32 + k;
            const float e = __expf(tr_s[i][j]);
            sc += e;
            s0 += e * elp_s[0][i];
            s1 += e * elp_s[1][i];
            s2 += e * elp_s[2][i];
            s3 += e * elp_s[3][i];
        }
        pc[sub][j] = sc;
        pa[sub][0][j] = s0; pa[sub][1][j] = s1;
        pa[sub][2][j] = s2; pa[sub][3][j] = s3;
    }
    // ---- gold path partials from prefetched indices (tr_s read-only) ----
    {
        float g = 0.f;
        #pragma unroll
        for (int k = 0; k < 8; ++k) {
            const int t = t0 + k * LL;
            if (t < SS - 1) g += tr_s[gf[k]][gs[k]];
        }
        #pragma unroll
        for (int off = 32; off > 0; off >>= 1) g += __shfl_xor(g, off);
        if (lane == 0) wred[wave] = g;
    }
    __syncthreads();                                        // (B)

    // ---- alpha[b,j] + per-wave forward LSE partials ----
    {
        const int b = tid >> 7;
        const int j = tid & (LL - 1);
        const float csum = pc[0][j] + pc[1][j] + pc[2][j] + pc[3][j];
        const float asum = pa[0][b][j] + pa[1][b][j] + pa[2][b][j] + pa[3][b][j];
        const float alpha = __logf(asum) + (float)(SS - 2) * __logf(csum);

        float wm = alpha;
        #pragma unroll
        for (int off = 32; off > 0; off >>= 1) wm = fmaxf(wm, __shfl_xor(wm, off));
        float wsum = __expf(alpha - wm);
        #pragma unroll
        for (int off = 32; off > 0; off >>= 1) wsum += __shfl_xor(wsum, off);
        if (lane == 0) { fm[wave] = wm; fs[wave] = wsum; }
    }
    __syncthreads();                                        // (C)

    if (tid < BB) {
        const float m0 = fm[2 * tid], m1 = fm[2 * tid + 1];
        const float mm = fmaxf(m0, m1);
        const float fwd = mm + __logf(fs[2 * tid] * __expf(m0 - mm)
                                    + fs[2 * tid + 1] * __expf(m1 - mm));
        const float gold = wred[2 * tid] + wred[2 * tid + 1];
        fm[tid] = emit_s[tid] + gold - fwd;   // reuse fm as loss scratch
    }
    __syncthreads();                                        // (D)
    if (tid == 0)
        out[0] = -(fm[0] + fm[1] + fm[2] + fm[3]) * (1.0f / BB);
}

extern "C" void kernel_launch(void* const* d_in, const int* in_sizes, int n_in,
                              void* d_out, int out_size, void* d_ws, size_t ws_size,
                              hipStream_t stream) {
    const float* pred       = (const float*)d_in[0];
    const int*   gt         = (const int*)d_in[1];
    const float* transition = (const float*)d_in[2];
    float* out = (float*)d_out;

    float* ws_part  = (float*)d_ws;        // 512 floats
    float* ws_elp   = ws_part + 512;       // 512 floats
    float* ws_trans = ws_part + 1024;      // 16384 floats, 4 KiB-aligned offset

    crf_rows_kernel<<<(BB * SS) / 8, 256, 0, stream>>>(
        pred, gt, transition, ws_part, ws_elp, ws_trans);
    crf_finish_kernel<<<1, 512, 0, stream>>>(gt, ws_part, ws_elp, ws_trans, out);
}